// Round 7
// baseline (194.517 us; speedup 1.0000x reference)
//
#include <hip/hip_runtime.h>
#include <hip/hip_bf16.h>

// N=8192, E=262144, F=512, H=16, C=7, G=2 (shapes fixed by the problem)

typedef float vfloat4 __attribute__((ext_vector_type(4)));

__global__ void k_init(float* deg, int* cntC, int* cntR, int N) {
  int i = blockIdx.x * blockDim.x + threadIdx.x;
  if (i < N) { deg[i] = 1.0f; cntC[i] = 0; cntR[i] = 0; }  // self-loop w=1 in deg
}

// histogram of edges by dest (CSC) and by src (CSR) + weighted degree
__global__ void k_hist(const int* __restrict__ row, const int* __restrict__ col,
                       const float* __restrict__ w,
                       int* cntC, int* cntR, float* deg, int E) {
  int e = blockIdx.x * blockDim.x + threadIdx.x;
  if (e < E) {
    int c = col[e];
    atomicAdd(&cntC[c], 1);
    atomicAdd(&deg[c], w[e]);
    atomicAdd(&cntR[row[e]], 1);
  }
}

// fused: dinv = deg^-1/2; two exclusive scans (cntC->offC/curC, cntR->offR/curR);
// zero grp/nag
__global__ __launch_bounds__(1024) void k_scan(const float* __restrict__ deg,
                                               float* __restrict__ dinv,
                                               const int* __restrict__ cntC,
                                               int* __restrict__ offC, int* __restrict__ curC,
                                               const int* __restrict__ cntR,
                                               int* __restrict__ offR, int* __restrict__ curR,
                                               float* grp, float* nag, int N, int E) {
  int t = threadIdx.x;
  if (t < 14) grp[t] = 0.f;
  if (t < 4) nag[t] = 0.f;
  int base = t * 8;
#pragma unroll
  for (int j = 0; j < 8; ++j) {
    int idx = base + j;
    if (idx < N) {
      float d = deg[idx];
      dinv[idx] = (d > 0.f) ? (1.0f / sqrtf(d)) : 0.f;
    }
  }
  __shared__ int sums[1024];
  // --- scan 1: cntC ---
  {
    int l[8];
    int s = 0;
#pragma unroll
    for (int j = 0; j < 8; ++j) {
      l[j] = s;
      int idx = base + j;
      s += (idx < N) ? cntC[idx] : 0;
    }
    sums[t] = s;
    __syncthreads();
    for (int d = 1; d < 1024; d <<= 1) {
      int v = (t >= d) ? sums[t - d] : 0;
      __syncthreads();
      sums[t] += v;
      __syncthreads();
    }
    int chunkoff = sums[t] - s;
#pragma unroll
    for (int j = 0; j < 8; ++j) {
      int idx = base + j;
      if (idx < N) {
        int o = chunkoff + l[j];
        offC[idx] = o;
        curC[idx] = o;
      }
    }
    if (t == 0) offC[N] = E;
  }
  __syncthreads();
  // --- scan 2: cntR ---
  {
    int l[8];
    int s = 0;
#pragma unroll
    for (int j = 0; j < 8; ++j) {
      l[j] = s;
      int idx = base + j;
      s += (idx < N) ? cntR[idx] : 0;
    }
    sums[t] = s;
    __syncthreads();
    for (int d = 1; d < 1024; d <<= 1) {
      int v = (t >= d) ? sums[t - d] : 0;
      __syncthreads();
      sums[t] += v;
      __syncthreads();
    }
    int chunkoff = sums[t] - s;
#pragma unroll
    for (int j = 0; j < 8; ++j) {
      int idx = base + j;
      if (idx < N) {
        int o = chunkoff + l[j];
        offR[idx] = o;
        curR[idx] = o;
      }
    }
    if (t == 0) offR[N] = E;
  }
}

// scatter edges into CSC (erow,ewt by dest) and CSR (ecol by src)
__global__ void k_fill(const int* __restrict__ row, const int* __restrict__ col,
                       const float* __restrict__ w, int* curC, int* curR,
                       int* __restrict__ erow, float* __restrict__ ewt,
                       int* __restrict__ ecol, int E) {
  int e = blockIdx.x * blockDim.x + threadIdx.x;
  if (e >= E) return;
  int r = row[e], c = col[e];
  int p = atomicAdd(&curC[c], 1);
  erow[p] = r;
  ewt[p] = w[e];
  int q = atomicAdd(&curR[r], 1);
  ecol[q] = c;
}

// hw1 = x @ W1
__global__ __launch_bounds__(256) void k_gemm1(
    const float* __restrict__ x, const float* __restrict__ W1,
    float* __restrict__ hw1, int N) {
  __shared__ float W1s[512 * 16];
  for (int i = threadIdx.x; i < 512 * 16; i += 256) W1s[i] = W1[i];
  __syncthreads();
  int row = blockIdx.x * 16 + (threadIdx.x >> 4);
  int h = threadIdx.x & 15;
  if (row >= N) return;
  const float4* xr = reinterpret_cast<const float4*>(x + (size_t)row * 512);
  float acc = 0.f;
#pragma unroll 8
  for (int k4 = 0; k4 < 128; ++k4) {
    float4 v = xr[k4];
    const float* wk = &W1s[k4 * 64 + h];
    acc = fmaf(v.x, wk[0], acc);
    acc = fmaf(v.y, wk[16], acc);
    acc = fmaf(v.z, wk[32], acc);
    acc = fmaf(v.w, wk[48], acc);
  }
  hw1[(size_t)row * 16 + h] = acc;
}

// conv1 gather: acc1[i][h] = b1[h] + dinv_i*sum_e dinv[r]*w*hw1[r][h] + dinv_i^2*hw1[i][h]
__global__ __launch_bounds__(256) void k_gather1(
    const int* __restrict__ off, const int* __restrict__ erow,
    const float* __restrict__ ewt, const float* __restrict__ dinv,
    const float* __restrict__ hw1, const float* __restrict__ b1,
    float* __restrict__ acc1, int N) {
  int node = blockIdx.x * 4 + (threadIdx.x >> 6);
  if (node >= N) return;
  int lane = threadIdx.x & 63;
  int s = lane >> 4, h = lane & 15;
  int beg = off[node], end = off[node + 1];
  float acc = 0.f;
  for (int j = beg + s; j < end; j += 4) {
    int r = erow[j];
    float cf = dinv[r] * ewt[j];
    acc = fmaf(hw1[(size_t)r * 16 + h], cf, acc);
  }
  acc += __shfl_down(acc, 32);
  acc += __shfl_down(acc, 16);
  if (s == 0) {
    float di = dinv[node];
    float self = hw1[(size_t)node * 16 + h];
    acc1[(size_t)node * 16 + h] = b1[h] + di * acc + di * di * self;
  }
}

// nf1 = relu(acc1); hw2 = nf1 @ W2
__global__ void k_p1(const float* __restrict__ acc1, const float* __restrict__ W2,
                     float* __restrict__ hw2, int N) {
  __shared__ float W2s[16 * 7];
  if (threadIdx.x < 112) W2s[threadIdx.x] = W2[threadIdx.x];
  __syncthreads();
  int i = blockIdx.x * blockDim.x + threadIdx.x;
  if (i >= N) return;
  float v[16];
#pragma unroll
  for (int h = 0; h < 16; ++h) v[h] = fmaxf(acc1[(size_t)i * 16 + h], 0.f);
#pragma unroll
  for (int c = 0; c < 7; ++c) {
    float s = 0.f;
#pragma unroll
    for (int h = 0; h < 16; ++h) s = fmaf(v[h], W2s[h * 7 + c], s);
    hw2[(size_t)i * 7 + c] = s;
  }
}

// conv2 gather: nf2[i][c] = b2[c] + dinv_i*sum_e dinv[r]*w*hw2[r][c] + dinv_i^2*hw2[i][c]
__global__ __launch_bounds__(256) void k_gather2(
    const int* __restrict__ off, const int* __restrict__ erow,
    const float* __restrict__ ewt, const float* __restrict__ dinv,
    const float* __restrict__ hw2, const float* __restrict__ b2,
    float* __restrict__ nf2, int N) {
  int node = blockIdx.x * 4 + (threadIdx.x >> 6);
  if (node >= N) return;
  int lane = threadIdx.x & 63;
  int s = lane >> 3, c = lane & 7;
  int beg = off[node], end = off[node + 1];
  float acc = 0.f;
  if (c < 7) {
    for (int j = beg + s; j < end; j += 8) {
      int r = erow[j];
      float cf = dinv[r] * ewt[j];
      acc = fmaf(hw2[(size_t)r * 7 + c], cf, acc);
    }
  }
  acc += __shfl_down(acc, 32);
  acc += __shfl_down(acc, 16);
  acc += __shfl_down(acc, 8);
  if (s == 0 && c < 7) {
    float di = dinv[node];
    nf2[(size_t)node * 7 + c] = b2[c] + di * acc + di * di * hw2[(size_t)node * 7 + c];
  }
}

// per-node: assignment (softmax over 2), keep mask, logp = log_softmax(nf2)
__global__ void k_p2(const float* __restrict__ nf2,
                     const float* __restrict__ Wf1, const float* __restrict__ bf1,
                     const float* __restrict__ Wf2, const float* __restrict__ bf2,
                     float* __restrict__ assign, float* __restrict__ keep,
                     float* __restrict__ logp, int N) {
  __shared__ float Wf1s[7 * 16], bf1s[16], Wf2s[16 * 2], bf2s[2];
  if (threadIdx.x < 112) Wf1s[threadIdx.x] = Wf1[threadIdx.x];
  if (threadIdx.x < 16) bf1s[threadIdx.x] = bf1[threadIdx.x];
  if (threadIdx.x < 32) Wf2s[threadIdx.x] = Wf2[threadIdx.x];
  if (threadIdx.x < 2) bf2s[threadIdx.x] = bf2[threadIdx.x];
  __syncthreads();
  int i = blockIdx.x * blockDim.x + threadIdx.x;
  if (i >= N) return;
  float f[7];
#pragma unroll
  for (int c = 0; c < 7; ++c) f[c] = nf2[(size_t)i * 7 + c];
  float z0 = bf2s[0], z1 = bf2s[1];
#pragma unroll
  for (int h = 0; h < 16; ++h) {
    float s = bf1s[h];
#pragma unroll
    for (int c = 0; c < 7; ++c) s = fmaf(f[c], Wf1s[c * 16 + h], s);
    float a = tanhf(s);
    z0 = fmaf(a, Wf2s[h * 2 + 0], z0);
    z1 = fmaf(a, Wf2s[h * 2 + 1], z1);
  }
  float m = fmaxf(z0, z1);
  float e0 = expf(z0 - m), e1 = expf(z1 - m);
  float inv = 1.f / (e0 + e1);
  float a0 = e0 * inv, a1 = e1 * inv;
  assign[2 * i] = a0;
  assign[2 * i + 1] = a1;
  keep[i] = (a0 >= a1) ? 1.f : 0.f;
  float mx = f[0];
#pragma unroll
  for (int c = 1; c < 7; ++c) mx = fmaxf(mx, f[c]);
  float se = 0.f;
#pragma unroll
  for (int c = 0; c < 7; ++c) se += expf(f[c] - mx);
  float lse = logf(se) + mx;
#pragma unroll
  for (int c = 0; c < 7; ++c) logp[(size_t)i * 7 + c] = f[c] - lse;
}

// fused: grp[g][c] = sum_i a[i][g]*nf2[i][c]; nag via CSC in-edge sums
__global__ __launch_bounds__(256) void k_nagrp(
    const int* __restrict__ off, const int* __restrict__ erow,
    const float* __restrict__ assign, const float* __restrict__ nf2,
    float* __restrict__ grp, float* __restrict__ nag, int N) {
  float p[18];
#pragma unroll
  for (int q = 0; q < 18; ++q) p[q] = 0.f;
  int stride = gridDim.x * blockDim.x;
  for (int node = blockIdx.x * blockDim.x + threadIdx.x; node < N; node += stride) {
    float a0 = assign[2 * node], a1 = assign[2 * node + 1];
    float f[7];
#pragma unroll
    for (int c = 0; c < 7; ++c) f[c] = nf2[(size_t)node * 7 + c];
#pragma unroll
    for (int c = 0; c < 7; ++c) {
      p[c] = fmaf(a0, f[c], p[c]);
      p[7 + c] = fmaf(a1, f[c], p[7 + c]);
    }
    float s0 = 0.f, s1 = 0.f;
    int beg = off[node], end = off[node + 1];
    for (int j = beg; j < end; ++j) {
      int r = erow[j];
      s0 += assign[2 * r];
      s1 += assign[2 * r + 1];
    }
    p[14] = fmaf(s0, a0, p[14]);
    p[15] = fmaf(s0, a1, p[15]);
    p[16] = fmaf(s1, a0, p[16]);
    p[17] = fmaf(s1, a1, p[17]);
  }
#pragma unroll
  for (int q = 0; q < 18; ++q) {
    float v = p[q];
    v += __shfl_down(v, 32);
    v += __shfl_down(v, 16);
    v += __shfl_down(v, 8);
    v += __shfl_down(v, 4);
    v += __shfl_down(v, 2);
    v += __shfl_down(v, 1);
    p[q] = v;
  }
  __shared__ float part[4][18];
  int wid = threadIdx.x >> 6, lane = threadIdx.x & 63;
  if (lane == 0) {
#pragma unroll
    for (int q = 0; q < 18; ++q) part[wid][q] = p[q];
  }
  __syncthreads();
  if (threadIdx.x < 18) {
    float v = part[0][threadIdx.x] + part[1][threadIdx.x] +
              part[2][threadIdx.x] + part[3][threadIdx.x];
    if (threadIdx.x < 14) atomicAdd(&grp[threadIdx.x], v);
    else atomicAdd(&nag[threadIdx.x - 14], v);
  }
}

// adj producer: one block per row. Accumulate the row's out-edge counts in
// LDS (keep-masked), then stream the full 32 KB row to global with
// nontemporal stores. Zero pass + scatter fused; no global atomics; adj never
// read -> never pulled into L3 dirty by RMW.
__global__ __launch_bounds__(256) void k_adjrow(
    const int* __restrict__ offR, const int* __restrict__ ecol,
    const float* __restrict__ keep, float* __restrict__ adj, int N) {
  __shared__ float rowbuf[8192];
  int r = blockIdx.x;
  vfloat4* dst = (vfloat4*)(adj + (size_t)r * N);
  int n4 = N / 4;
  if (keep[r] != 0.f) {
    for (int i = threadIdx.x; i < n4; i += 256)
      ((vfloat4*)rowbuf)[i] = (vfloat4){0.f, 0.f, 0.f, 0.f};
    __syncthreads();
    int beg = offR[r], end = offR[r + 1];
    for (int j = beg + threadIdx.x; j < end; j += 256)
      atomicAdd(&rowbuf[ecol[j]], 1.0f);
    __syncthreads();
    for (int i = threadIdx.x; i < n4; i += 256)
      __builtin_nontemporal_store(((vfloat4*)rowbuf)[i], &dst[i]);
  } else {
    vfloat4 z = {0.f, 0.f, 0.f, 0.f};
    for (int i = threadIdx.x; i < n4; i += 256)
      __builtin_nontemporal_store(z, &dst[i]);
  }
}

__global__ void k_final(const float* __restrict__ grp, const float* __restrict__ nag,
                        float* __restrict__ o_ge, float* __restrict__ o_pos,
                        float* __restrict__ o_neg, float* __restrict__ o_pp) {
  int t = threadIdx.x;
  if (t < 7) {
    float g0 = grp[t], g1 = grp[7 + t];
    o_pos[t] = fminf(fmaxf(g0, -100.f), 100.f);
    o_neg[t] = fminf(fmaxf(g1, -100.f), 100.f);
    o_ge[t] = 0.5f * (g0 + g1);
  }
  if (t == 0) {
    float n00 = nag[0], n01 = nag[1], n10 = nag[2], n11 = nag[3];
    float d0 = n00 / fmaxf(fabsf(n00) + fabsf(n01), 1e-12f);
    float d1 = n11 / fmaxf(fabsf(n10) + fabsf(n11), 1e-12f);
    o_pp[0] = 0.5f * ((d0 - 1.f) * (d0 - 1.f) + (d1 - 1.f) * (d1 - 1.f));
  }
}

extern "C" void kernel_launch(void* const* d_in, const int* in_sizes, int n_in,
                              void* d_out, int out_size, void* d_ws, size_t ws_size,
                              hipStream_t stream) {
  const float* x   = (const float*)d_in[0];
  const int*   ei  = (const int*)d_in[1];
  const float* ew  = (const float*)d_in[2];
  const float* W1  = (const float*)d_in[3];
  const float* b1  = (const float*)d_in[4];
  const float* W2  = (const float*)d_in[5];
  const float* b2  = (const float*)d_in[6];
  const float* Wf1 = (const float*)d_in[7];
  const float* bf1 = (const float*)d_in[8];
  const float* Wf2 = (const float*)d_in[9];
  const float* bf2 = (const float*)d_in[10];

  const int E = in_sizes[2];
  const int F = in_sizes[3] / 16;  // 512
  const int N = in_sizes[0] / F;   // 8192
  const int* row = ei;
  const int* col = ei + E;

  float* ws = (float*)d_ws;
  float* deg    = ws; ws += N;
  float* dinv   = ws; ws += N;
  int*   cntC   = (int*)ws; ws += N;
  int*   offC   = (int*)ws; ws += N + 1;
  int*   curC   = (int*)ws; ws += N;
  int*   cntR   = (int*)ws; ws += N;
  int*   offR   = (int*)ws; ws += N + 1;
  int*   curR   = (int*)ws; ws += N;
  int*   erow   = (int*)ws; ws += E;
  float* ewt    = ws; ws += E;
  int*   ecol   = (int*)ws; ws += E;
  float* hw1    = ws; ws += (size_t)N * 16;
  float* acc1   = ws; ws += (size_t)N * 16;
  float* hw2    = ws; ws += (size_t)N * 7;
  float* assign = ws; ws += (size_t)N * 2;
  float* keep   = ws; ws += N;
  float* grp    = ws; ws += 16;
  float* nag    = ws; ws += 8;

  float* out = (float*)d_out;
  size_t NN = (size_t)N * N;
  float* o_adj  = out;
  float* o_nf2  = out + NN;
  float* o_ge   = o_nf2 + (size_t)N * 7;
  float* o_pos  = o_ge + 7;
  float* o_neg  = o_pos + 7;
  float* o_pp   = o_neg + 7;
  float* o_logp = o_pp + 1;

  int nb_N = (N + 255) / 256;
  int nb_E = (E + 255) / 256;
  int nb_W = (N + 3) / 4;  // one wave per node, 4 waves/block
  k_init<<<nb_N, 256, 0, stream>>>(deg, cntC, cntR, N);
  k_hist<<<nb_E, 256, 0, stream>>>(row, col, ew, cntC, cntR, deg, E);
  k_scan<<<1, 1024, 0, stream>>>(deg, dinv, cntC, offC, curC, cntR, offR, curR,
                                 grp, nag, N, E);
  k_fill<<<nb_E, 256, 0, stream>>>(row, col, ew, curC, curR, erow, ewt, ecol, E);
  k_gemm1<<<N / 16, 256, 0, stream>>>(x, W1, hw1, N);
  k_gather1<<<nb_W, 256, 0, stream>>>(offC, erow, ewt, dinv, hw1, b1, acc1, N);
  k_p1<<<nb_N, 256, 0, stream>>>(acc1, W2, hw2, N);
  k_gather2<<<nb_W, 256, 0, stream>>>(offC, erow, ewt, dinv, hw2, b2, o_nf2, N);
  k_p2<<<nb_N, 256, 0, stream>>>(o_nf2, Wf1, bf1, Wf2, bf2, assign, keep, o_logp, N);
  k_nagrp<<<32, 256, 0, stream>>>(offC, erow, assign, o_nf2, grp, nag, N);
  k_adjrow<<<N, 256, 0, stream>>>(offR, ecol, keep, o_adj, N);
  k_final<<<1, 64, 0, stream>>>(grp, nag, o_ge, o_pos, o_neg, o_pp);
}

// Round 8
// 180.656 us; speedup vs baseline: 1.0767x; 1.0767x over previous
//
#include <hip/hip_runtime.h>
#include <hip/hip_bf16.h>

// N=8192, E=262144, F=512, H=16, C=7, G=2 (shapes fixed by the problem)

typedef float vfloat4 __attribute__((ext_vector_type(4)));

__global__ void k_init(float* deg, int* cnt, int N) {
  int i = blockIdx.x * blockDim.x + threadIdx.x;
  if (i < N) { deg[i] = 1.0f; cnt[i] = 0; }  // self-loop weight 1 in deg
}

// zero-fill adj (256 MiB) with fully-streaming stores: sc0 sc1 nt bypasses
// the L3-dirty-resident write-hit path (~1.7 TB/s) seen when the buffer
// exactly fits Infinity Cache.
__global__ __launch_bounds__(256) void k_zero(float* __restrict__ p, size_t n4) {
  size_t stride = (size_t)gridDim.x * blockDim.x;
  vfloat4 z = {0.f, 0.f, 0.f, 0.f};
  for (size_t i = (size_t)blockIdx.x * blockDim.x + threadIdx.x; i < n4; i += stride) {
    float* addr = p + i * 4;
    asm volatile("global_store_dwordx4 %0, %1, off sc0 sc1 nt"
                 :: "v"(addr), "v"(z) : "memory");
  }
}

// histogram of edge destinations + weighted degree in one pass
__global__ void k_hist(const int* __restrict__ col, const float* __restrict__ w,
                       int* cnt, float* deg, int E) {
  int e = blockIdx.x * blockDim.x + threadIdx.x;
  if (e < E) {
    int c = col[e];
    atomicAdd(&cnt[c], 1);
    atomicAdd(&deg[c], w[e]);
  }
}

// fused: dinv = deg^-1/2; exclusive scan cnt -> off/cur; zero grp/nag
__global__ __launch_bounds__(1024) void k_scan(const float* __restrict__ deg,
                                               float* __restrict__ dinv,
                                               const int* __restrict__ cnt,
                                               int* __restrict__ off,
                                               int* __restrict__ cur,
                                               float* grp, float* nag, int N, int E) {
  int t = threadIdx.x;
  if (t < 14) grp[t] = 0.f;
  if (t < 4) nag[t] = 0.f;
  int base = t * 8;
#pragma unroll
  for (int j = 0; j < 8; ++j) {
    int idx = base + j;
    if (idx < N) {
      float d = deg[idx];
      dinv[idx] = (d > 0.f) ? (1.0f / sqrtf(d)) : 0.f;
    }
  }
  __shared__ int sums[1024];
  int l[8];
  int s = 0;
#pragma unroll
  for (int j = 0; j < 8; ++j) {
    l[j] = s;
    int idx = base + j;
    s += (idx < N) ? cnt[idx] : 0;
  }
  sums[t] = s;
  __syncthreads();
  for (int d = 1; d < 1024; d <<= 1) {
    int v = (t >= d) ? sums[t - d] : 0;
    __syncthreads();
    sums[t] += v;
    __syncthreads();
  }
  int chunkoff = sums[t] - s;
#pragma unroll
  for (int j = 0; j < 8; ++j) {
    int idx = base + j;
    if (idx < N) {
      int o = chunkoff + l[j];
      off[idx] = o;
      cur[idx] = o;
    }
  }
  if (t == 0) off[N] = E;
}

// scatter edges into CSC order: per dest node, list of (src row, weight)
__global__ void k_fill(const int* __restrict__ row, const int* __restrict__ col,
                       const float* __restrict__ w, int* cur,
                       int* __restrict__ erow, float* __restrict__ ewt, int E) {
  int e = blockIdx.x * blockDim.x + threadIdx.x;
  if (e >= E) return;
  int c = col[e];
  int p = atomicAdd(&cur[c], 1);
  erow[p] = row[e];
  ewt[p] = w[e];
}

// hw1 = x @ W1
__global__ __launch_bounds__(256) void k_gemm1(
    const float* __restrict__ x, const float* __restrict__ W1,
    float* __restrict__ hw1, int N) {
  __shared__ float W1s[512 * 16];
  for (int i = threadIdx.x; i < 512 * 16; i += 256) W1s[i] = W1[i];
  __syncthreads();
  int row = blockIdx.x * 16 + (threadIdx.x >> 4);
  int h = threadIdx.x & 15;
  if (row >= N) return;
  const float4* xr = reinterpret_cast<const float4*>(x + (size_t)row * 512);
  float acc = 0.f;
#pragma unroll 8
  for (int k4 = 0; k4 < 128; ++k4) {
    float4 v = xr[k4];
    const float* wk = &W1s[k4 * 64 + h];
    acc = fmaf(v.x, wk[0], acc);
    acc = fmaf(v.y, wk[16], acc);
    acc = fmaf(v.z, wk[32], acc);
    acc = fmaf(v.w, wk[48], acc);
  }
  hw1[(size_t)row * 16 + h] = acc;
}

// conv1 gather: acc1[i][h] = b1[h] + dinv_i*sum_e dinv[r]*w*hw1[r][h] + dinv_i^2*hw1[i][h]
__global__ __launch_bounds__(256) void k_gather1(
    const int* __restrict__ off, const int* __restrict__ erow,
    const float* __restrict__ ewt, const float* __restrict__ dinv,
    const float* __restrict__ hw1, const float* __restrict__ b1,
    float* __restrict__ acc1, int N) {
  int node = blockIdx.x * 4 + (threadIdx.x >> 6);
  if (node >= N) return;
  int lane = threadIdx.x & 63;
  int s = lane >> 4, h = lane & 15;
  int beg = off[node], end = off[node + 1];
  float acc = 0.f;
  for (int j = beg + s; j < end; j += 4) {
    int r = erow[j];
    float cf = dinv[r] * ewt[j];
    acc = fmaf(hw1[(size_t)r * 16 + h], cf, acc);
  }
  acc += __shfl_down(acc, 32);
  acc += __shfl_down(acc, 16);
  if (s == 0) {
    float di = dinv[node];
    float self = hw1[(size_t)node * 16 + h];
    acc1[(size_t)node * 16 + h] = b1[h] + di * acc + di * di * self;
  }
}

// nf1 = relu(acc1); hw2 = nf1 @ W2
__global__ void k_p1(const float* __restrict__ acc1, const float* __restrict__ W2,
                     float* __restrict__ hw2, int N) {
  __shared__ float W2s[16 * 7];
  if (threadIdx.x < 112) W2s[threadIdx.x] = W2[threadIdx.x];
  __syncthreads();
  int i = blockIdx.x * blockDim.x + threadIdx.x;
  if (i >= N) return;
  float v[16];
#pragma unroll
  for (int h = 0; h < 16; ++h) v[h] = fmaxf(acc1[(size_t)i * 16 + h], 0.f);
#pragma unroll
  for (int c = 0; c < 7; ++c) {
    float s = 0.f;
#pragma unroll
    for (int h = 0; h < 16; ++h) s = fmaf(v[h], W2s[h * 7 + c], s);
    hw2[(size_t)i * 7 + c] = s;
  }
}

// conv2 gather: nf2[i][c] = b2[c] + dinv_i*sum_e dinv[r]*w*hw2[r][c] + dinv_i^2*hw2[i][c]
__global__ __launch_bounds__(256) void k_gather2(
    const int* __restrict__ off, const int* __restrict__ erow,
    const float* __restrict__ ewt, const float* __restrict__ dinv,
    const float* __restrict__ hw2, const float* __restrict__ b2,
    float* __restrict__ nf2, int N) {
  int node = blockIdx.x * 4 + (threadIdx.x >> 6);
  if (node >= N) return;
  int lane = threadIdx.x & 63;
  int s = lane >> 3, c = lane & 7;
  int beg = off[node], end = off[node + 1];
  float acc = 0.f;
  if (c < 7) {
    for (int j = beg + s; j < end; j += 8) {
      int r = erow[j];
      float cf = dinv[r] * ewt[j];
      acc = fmaf(hw2[(size_t)r * 7 + c], cf, acc);
    }
  }
  acc += __shfl_down(acc, 32);
  acc += __shfl_down(acc, 16);
  acc += __shfl_down(acc, 8);
  if (s == 0 && c < 7) {
    float di = dinv[node];
    nf2[(size_t)node * 7 + c] = b2[c] + di * acc + di * di * hw2[(size_t)node * 7 + c];
  }
}

// per-node: assignment (softmax over 2), keep mask, logp = log_softmax(nf2)
__global__ void k_p2(const float* __restrict__ nf2,
                     const float* __restrict__ Wf1, const float* __restrict__ bf1,
                     const float* __restrict__ Wf2, const float* __restrict__ bf2,
                     float* __restrict__ assign, float* __restrict__ keep,
                     float* __restrict__ logp, int N) {
  __shared__ float Wf1s[7 * 16], bf1s[16], Wf2s[16 * 2], bf2s[2];
  if (threadIdx.x < 112) Wf1s[threadIdx.x] = Wf1[threadIdx.x];
  if (threadIdx.x < 16) bf1s[threadIdx.x] = bf1[threadIdx.x];
  if (threadIdx.x < 32) Wf2s[threadIdx.x] = Wf2[threadIdx.x];
  if (threadIdx.x < 2) bf2s[threadIdx.x] = bf2[threadIdx.x];
  __syncthreads();
  int i = blockIdx.x * blockDim.x + threadIdx.x;
  if (i >= N) return;
  float f[7];
#pragma unroll
  for (int c = 0; c < 7; ++c) f[c] = nf2[(size_t)i * 7 + c];
  float z0 = bf2s[0], z1 = bf2s[1];
#pragma unroll
  for (int h = 0; h < 16; ++h) {
    float s = bf1s[h];
#pragma unroll
    for (int c = 0; c < 7; ++c) s = fmaf(f[c], Wf1s[c * 16 + h], s);
    float a = tanhf(s);
    z0 = fmaf(a, Wf2s[h * 2 + 0], z0);
    z1 = fmaf(a, Wf2s[h * 2 + 1], z1);
  }
  float m = fmaxf(z0, z1);
  float e0 = expf(z0 - m), e1 = expf(z1 - m);
  float inv = 1.f / (e0 + e1);
  float a0 = e0 * inv, a1 = e1 * inv;
  assign[2 * i] = a0;
  assign[2 * i + 1] = a1;
  keep[i] = (a0 >= a1) ? 1.f : 0.f;
  float mx = f[0];
#pragma unroll
  for (int c = 1; c < 7; ++c) mx = fmaxf(mx, f[c]);
  float se = 0.f;
#pragma unroll
  for (int c = 0; c < 7; ++c) se += expf(f[c] - mx);
  float lse = logf(se) + mx;
#pragma unroll
  for (int c = 0; c < 7; ++c) logp[(size_t)i * 7 + c] = f[c] - lse;
}

// fused: grp[g][c] = sum_i a[i][g]*nf2[i][c]; nag via CSC in-edge sums
__global__ __launch_bounds__(256) void k_nagrp(
    const int* __restrict__ off, const int* __restrict__ erow,
    const float* __restrict__ assign, const float* __restrict__ nf2,
    float* __restrict__ grp, float* __restrict__ nag, int N) {
  float p[18];
#pragma unroll
  for (int q = 0; q < 18; ++q) p[q] = 0.f;
  int stride = gridDim.x * blockDim.x;
  for (int node = blockIdx.x * blockDim.x + threadIdx.x; node < N; node += stride) {
    float a0 = assign[2 * node], a1 = assign[2 * node + 1];
    float f[7];
#pragma unroll
    for (int c = 0; c < 7; ++c) f[c] = nf2[(size_t)node * 7 + c];
#pragma unroll
    for (int c = 0; c < 7; ++c) {
      p[c] = fmaf(a0, f[c], p[c]);
      p[7 + c] = fmaf(a1, f[c], p[7 + c]);
    }
    float s0 = 0.f, s1 = 0.f;
    int beg = off[node], end = off[node + 1];
    for (int j = beg; j < end; ++j) {
      int r = erow[j];
      s0 += assign[2 * r];
      s1 += assign[2 * r + 1];
    }
    p[14] = fmaf(s0, a0, p[14]);
    p[15] = fmaf(s0, a1, p[15]);
    p[16] = fmaf(s1, a0, p[16]);
    p[17] = fmaf(s1, a1, p[17]);
  }
#pragma unroll
  for (int q = 0; q < 18; ++q) {
    float v = p[q];
    v += __shfl_down(v, 32);
    v += __shfl_down(v, 16);
    v += __shfl_down(v, 8);
    v += __shfl_down(v, 4);
    v += __shfl_down(v, 2);
    v += __shfl_down(v, 1);
    p[q] = v;
  }
  __shared__ float part[4][18];
  int wid = threadIdx.x >> 6, lane = threadIdx.x & 63;
  if (lane == 0) {
#pragma unroll
    for (int q = 0; q < 18; ++q) part[wid][q] = p[q];
  }
  __syncthreads();
  if (threadIdx.x < 18) {
    float v = part[0][threadIdx.x] + part[1][threadIdx.x] +
              part[2][threadIdx.x] + part[3][threadIdx.x];
    if (threadIdx.x < 14) atomicAdd(&grp[threadIdx.x], v);
    else atomicAdd(&nag[threadIdx.x - 14], v);
  }
}

// adj scatter only (uncontended, fire-and-forget atomics)
__global__ void k_adj(const int* __restrict__ row, const int* __restrict__ col,
                      const float* __restrict__ keep, float* __restrict__ adj,
                      int N, int E) {
  int e = blockIdx.x * blockDim.x + threadIdx.x;
  if (e >= E) return;
  int r = row[e], c = col[e];
  if (keep[r] != 0.f) atomicAdd(&adj[(size_t)r * N + c], 1.0f);
}

__global__ void k_final(const float* __restrict__ grp, const float* __restrict__ nag,
                        float* __restrict__ o_ge, float* __restrict__ o_pos,
                        float* __restrict__ o_neg, float* __restrict__ o_pp) {
  int t = threadIdx.x;
  if (t < 7) {
    float g0 = grp[t], g1 = grp[7 + t];
    o_pos[t] = fminf(fmaxf(g0, -100.f), 100.f);
    o_neg[t] = fminf(fmaxf(g1, -100.f), 100.f);
    o_ge[t] = 0.5f * (g0 + g1);
  }
  if (t == 0) {
    float n00 = nag[0], n01 = nag[1], n10 = nag[2], n11 = nag[3];
    float d0 = n00 / fmaxf(fabsf(n00) + fabsf(n01), 1e-12f);
    float d1 = n11 / fmaxf(fabsf(n10) + fabsf(n11), 1e-12f);
    o_pp[0] = 0.5f * ((d0 - 1.f) * (d0 - 1.f) + (d1 - 1.f) * (d1 - 1.f));
  }
}

extern "C" void kernel_launch(void* const* d_in, const int* in_sizes, int n_in,
                              void* d_out, int out_size, void* d_ws, size_t ws_size,
                              hipStream_t stream) {
  const float* x   = (const float*)d_in[0];
  const int*   ei  = (const int*)d_in[1];
  const float* ew  = (const float*)d_in[2];
  const float* W1  = (const float*)d_in[3];
  const float* b1  = (const float*)d_in[4];
  const float* W2  = (const float*)d_in[5];
  const float* b2  = (const float*)d_in[6];
  const float* Wf1 = (const float*)d_in[7];
  const float* bf1 = (const float*)d_in[8];
  const float* Wf2 = (const float*)d_in[9];
  const float* bf2 = (const float*)d_in[10];

  const int E = in_sizes[2];
  const int F = in_sizes[3] / 16;  // 512
  const int N = in_sizes[0] / F;   // 8192
  const int* row = ei;
  const int* col = ei + E;

  float* ws = (float*)d_ws;
  float* deg    = ws; ws += N;
  float* dinv   = ws; ws += N;
  int*   cnt    = (int*)ws; ws += N;
  int*   off    = (int*)ws; ws += N + 1;
  int*   cur    = (int*)ws; ws += N;
  int*   erow   = (int*)ws; ws += E;
  float* ewt    = ws; ws += E;
  float* hw1    = ws; ws += (size_t)N * 16;
  float* acc1   = ws; ws += (size_t)N * 16;
  float* hw2    = ws; ws += (size_t)N * 7;
  float* assign = ws; ws += (size_t)N * 2;
  float* keep   = ws; ws += N;
  float* grp    = ws; ws += 16;
  float* nag    = ws; ws += 8;

  float* out = (float*)d_out;
  size_t NN = (size_t)N * N;
  float* o_adj  = out;
  float* o_nf2  = out + NN;
  float* o_ge   = o_nf2 + (size_t)N * 7;
  float* o_pos  = o_ge + 7;
  float* o_neg  = o_pos + 7;
  float* o_pp   = o_neg + 7;
  float* o_logp = o_pp + 1;

  int nb_N = (N + 255) / 256;
  int nb_E = (E + 255) / 256;
  int nb_W = (N + 3) / 4;  // one wave per node, 4 waves/block
  k_zero<<<4096, 256, 0, stream>>>(o_adj, NN / 4);
  k_init<<<nb_N, 256, 0, stream>>>(deg, cnt, N);
  k_hist<<<nb_E, 256, 0, stream>>>(col, ew, cnt, deg, E);
  k_scan<<<1, 1024, 0, stream>>>(deg, dinv, cnt, off, cur, grp, nag, N, E);
  k_fill<<<nb_E, 256, 0, stream>>>(row, col, ew, cur, erow, ewt, E);
  k_gemm1<<<N / 16, 256, 0, stream>>>(x, W1, hw1, N);
  k_gather1<<<nb_W, 256, 0, stream>>>(off, erow, ewt, dinv, hw1, b1, acc1, N);
  k_p1<<<nb_N, 256, 0, stream>>>(acc1, W2, hw2, N);
  k_gather2<<<nb_W, 256, 0, stream>>>(off, erow, ewt, dinv, hw2, b2, o_nf2, N);
  k_p2<<<nb_N, 256, 0, stream>>>(o_nf2, Wf1, bf1, Wf2, bf2, assign, keep, o_logp, N);
  k_nagrp<<<32, 256, 0, stream>>>(off, erow, assign, o_nf2, grp, nag, N);
  k_adj<<<nb_E, 256, 0, stream>>>(row, col, keep, o_adj, N, E);
  k_final<<<1, 64, 0, stream>>>(grp, nag, o_ge, o_pos, o_neg, o_pp);
}

// Round 9
// 167.700 us; speedup vs baseline: 1.1599x; 1.0773x over previous
//
#include <hip/hip_runtime.h>
#include <hip/hip_bf16.h>

// N=8192, E=262144, F=512, H=16, C=7, G=2 (shapes fixed by the problem)

typedef float vfloat4 __attribute__((ext_vector_type(4)));

// streaming zero-store helper: nt + sc0/sc1 (best measured flavor for the
// L3-resident adj buffer). idx/cnt in float4 units.
__device__ __forceinline__ void fill_tail(float* __restrict__ adj,
                                          size_t start, size_t count,
                                          unsigned tid, unsigned nthr) {
  vfloat4 z = {0.f, 0.f, 0.f, 0.f};
  for (size_t i = start + tid; i < start + count; i += nthr) {
    float* addr = adj + i * 4;
    asm volatile("global_store_dwordx4 %0, %1, off sc0 sc1 nt"
                 :: "v"(addr), "v"(z) : "memory");
  }
}

__global__ void k_init(float* deg, int* cnt, int N) {
  int i = blockIdx.x * blockDim.x + threadIdx.x;
  if (i < N) { deg[i] = 1.0f; cnt[i] = 0; }  // self-loop weight 1 in deg
}

// residual zero-fill of adj
__global__ __launch_bounds__(256) void k_zero(float* __restrict__ p,
                                              size_t start, size_t count) {
  fill_tail(p, start, count,
            blockIdx.x * blockDim.x + threadIdx.x, gridDim.x * blockDim.x);
}

// histogram of edge destinations + weighted degree + fill slice
__global__ void k_hist(const int* __restrict__ col, const float* __restrict__ w,
                       int* cnt, float* deg, int E,
                       float* __restrict__ adj, size_t fo, size_t fc) {
  int e = blockIdx.x * blockDim.x + threadIdx.x;
  if (e < E) {
    int c = col[e];
    atomicAdd(&cnt[c], 1);
    atomicAdd(&deg[c], w[e]);
  }
  fill_tail(adj, fo, fc, blockIdx.x * blockDim.x + threadIdx.x,
            gridDim.x * blockDim.x);
}

// fused: dinv = deg^-1/2; exclusive scan cnt -> off/cur; zero grp/nag
__global__ __launch_bounds__(1024) void k_scan(const float* __restrict__ deg,
                                               float* __restrict__ dinv,
                                               const int* __restrict__ cnt,
                                               int* __restrict__ off,
                                               int* __restrict__ cur,
                                               float* grp, float* nag, int N, int E) {
  int t = threadIdx.x;
  if (t < 14) grp[t] = 0.f;
  if (t < 4) nag[t] = 0.f;
  int base = t * 8;
#pragma unroll
  for (int j = 0; j < 8; ++j) {
    int idx = base + j;
    if (idx < N) {
      float d = deg[idx];
      dinv[idx] = (d > 0.f) ? (1.0f / sqrtf(d)) : 0.f;
    }
  }
  __shared__ int sums[1024];
  int l[8];
  int s = 0;
#pragma unroll
  for (int j = 0; j < 8; ++j) {
    l[j] = s;
    int idx = base + j;
    s += (idx < N) ? cnt[idx] : 0;
  }
  sums[t] = s;
  __syncthreads();
  for (int d = 1; d < 1024; d <<= 1) {
    int v = (t >= d) ? sums[t - d] : 0;
    __syncthreads();
    sums[t] += v;
    __syncthreads();
  }
  int chunkoff = sums[t] - s;
#pragma unroll
  for (int j = 0; j < 8; ++j) {
    int idx = base + j;
    if (idx < N) {
      int o = chunkoff + l[j];
      off[idx] = o;
      cur[idx] = o;
    }
  }
  if (t == 0) off[N] = E;
}

// scatter edges into CSC order + fill slice
__global__ void k_fill(const int* __restrict__ row, const int* __restrict__ col,
                       const float* __restrict__ w, int* cur,
                       int* __restrict__ erow, float* __restrict__ ewt, int E,
                       float* __restrict__ adj, size_t fo, size_t fc) {
  int e = blockIdx.x * blockDim.x + threadIdx.x;
  if (e < E) {
    int c = col[e];
    int p = atomicAdd(&cur[c], 1);
    erow[p] = row[e];
    ewt[p] = w[e];
  }
  fill_tail(adj, fo, fc, blockIdx.x * blockDim.x + threadIdx.x,
            gridDim.x * blockDim.x);
}

// hw1 = x @ W1  + fill slice
__global__ __launch_bounds__(256) void k_gemm1(
    const float* __restrict__ x, const float* __restrict__ W1,
    float* __restrict__ hw1, int N,
    float* __restrict__ adj, size_t fo, size_t fc) {
  __shared__ float W1s[512 * 16];
  for (int i = threadIdx.x; i < 512 * 16; i += 256) W1s[i] = W1[i];
  __syncthreads();
  int row = blockIdx.x * 16 + (threadIdx.x >> 4);
  int h = threadIdx.x & 15;
  const float4* xr = reinterpret_cast<const float4*>(x + (size_t)row * 512);
  float acc = 0.f;
#pragma unroll 8
  for (int k4 = 0; k4 < 128; ++k4) {
    float4 v = xr[k4];
    const float* wk = &W1s[k4 * 64 + h];
    acc = fmaf(v.x, wk[0], acc);
    acc = fmaf(v.y, wk[16], acc);
    acc = fmaf(v.z, wk[32], acc);
    acc = fmaf(v.w, wk[48], acc);
  }
  hw1[(size_t)row * 16 + h] = acc;
  fill_tail(adj, fo, fc, blockIdx.x * blockDim.x + threadIdx.x,
            gridDim.x * blockDim.x);
}

// conv1 gather + fill slice
__global__ __launch_bounds__(256) void k_gather1(
    const int* __restrict__ off, const int* __restrict__ erow,
    const float* __restrict__ ewt, const float* __restrict__ dinv,
    const float* __restrict__ hw1, const float* __restrict__ b1,
    float* __restrict__ acc1, int N,
    float* __restrict__ adj, size_t fo, size_t fc) {
  int node = blockIdx.x * 4 + (threadIdx.x >> 6);
  int lane = threadIdx.x & 63;
  int s = lane >> 4, h = lane & 15;
  int beg = off[node], end = off[node + 1];
  float acc = 0.f;
  for (int j = beg + s; j < end; j += 4) {
    int r = erow[j];
    float cf = dinv[r] * ewt[j];
    acc = fmaf(hw1[(size_t)r * 16 + h], cf, acc);
  }
  acc += __shfl_down(acc, 32);
  acc += __shfl_down(acc, 16);
  if (s == 0) {
    float di = dinv[node];
    float self = hw1[(size_t)node * 16 + h];
    acc1[(size_t)node * 16 + h] = b1[h] + di * acc + di * di * self;
  }
  fill_tail(adj, fo, fc, blockIdx.x * blockDim.x + threadIdx.x,
            gridDim.x * blockDim.x);
}

// nf1 = relu(acc1); hw2 = nf1 @ W2
__global__ void k_p1(const float* __restrict__ acc1, const float* __restrict__ W2,
                     float* __restrict__ hw2, int N) {
  __shared__ float W2s[16 * 7];
  if (threadIdx.x < 112) W2s[threadIdx.x] = W2[threadIdx.x];
  __syncthreads();
  int i = blockIdx.x * blockDim.x + threadIdx.x;
  if (i >= N) return;
  float v[16];
#pragma unroll
  for (int h = 0; h < 16; ++h) v[h] = fmaxf(acc1[(size_t)i * 16 + h], 0.f);
#pragma unroll
  for (int c = 0; c < 7; ++c) {
    float s = 0.f;
#pragma unroll
    for (int h = 0; h < 16; ++h) s = fmaf(v[h], W2s[h * 7 + c], s);
    hw2[(size_t)i * 7 + c] = s;
  }
}

// conv2 gather + fill slice
__global__ __launch_bounds__(256) void k_gather2(
    const int* __restrict__ off, const int* __restrict__ erow,
    const float* __restrict__ ewt, const float* __restrict__ dinv,
    const float* __restrict__ hw2, const float* __restrict__ b2,
    float* __restrict__ nf2, int N,
    float* __restrict__ adj, size_t fo, size_t fc) {
  int node = blockIdx.x * 4 + (threadIdx.x >> 6);
  int lane = threadIdx.x & 63;
  int s = lane >> 3, c = lane & 7;
  int beg = off[node], end = off[node + 1];
  float acc = 0.f;
  if (c < 7) {
    for (int j = beg + s; j < end; j += 8) {
      int r = erow[j];
      float cf = dinv[r] * ewt[j];
      acc = fmaf(hw2[(size_t)r * 7 + c], cf, acc);
    }
  }
  acc += __shfl_down(acc, 32);
  acc += __shfl_down(acc, 16);
  acc += __shfl_down(acc, 8);
  if (s == 0 && c < 7) {
    float di = dinv[node];
    nf2[(size_t)node * 7 + c] = b2[c] + di * acc + di * di * hw2[(size_t)node * 7 + c];
  }
  fill_tail(adj, fo, fc, blockIdx.x * blockDim.x + threadIdx.x,
            gridDim.x * blockDim.x);
}

// per-node: assignment (softmax over 2), keep mask, logp = log_softmax(nf2)
__global__ void k_p2(const float* __restrict__ nf2,
                     const float* __restrict__ Wf1, const float* __restrict__ bf1,
                     const float* __restrict__ Wf2, const float* __restrict__ bf2,
                     float* __restrict__ assign, float* __restrict__ keep,
                     float* __restrict__ logp, int N) {
  __shared__ float Wf1s[7 * 16], bf1s[16], Wf2s[16 * 2], bf2s[2];
  if (threadIdx.x < 112) Wf1s[threadIdx.x] = Wf1[threadIdx.x];
  if (threadIdx.x < 16) bf1s[threadIdx.x] = bf1[threadIdx.x];
  if (threadIdx.x < 32) Wf2s[threadIdx.x] = Wf2[threadIdx.x];
  if (threadIdx.x < 2) bf2s[threadIdx.x] = bf2[threadIdx.x];
  __syncthreads();
  int i = blockIdx.x * blockDim.x + threadIdx.x;
  if (i >= N) return;
  float f[7];
#pragma unroll
  for (int c = 0; c < 7; ++c) f[c] = nf2[(size_t)i * 7 + c];
  float z0 = bf2s[0], z1 = bf2s[1];
#pragma unroll
  for (int h = 0; h < 16; ++h) {
    float s = bf1s[h];
#pragma unroll
    for (int c = 0; c < 7; ++c) s = fmaf(f[c], Wf1s[c * 16 + h], s);
    float a = tanhf(s);
    z0 = fmaf(a, Wf2s[h * 2 + 0], z0);
    z1 = fmaf(a, Wf2s[h * 2 + 1], z1);
  }
  float m = fmaxf(z0, z1);
  float e0 = expf(z0 - m), e1 = expf(z1 - m);
  float inv = 1.f / (e0 + e1);
  float a0 = e0 * inv, a1 = e1 * inv;
  assign[2 * i] = a0;
  assign[2 * i + 1] = a1;
  keep[i] = (a0 >= a1) ? 1.f : 0.f;
  float mx = f[0];
#pragma unroll
  for (int c = 1; c < 7; ++c) mx = fmaxf(mx, f[c]);
  float se = 0.f;
#pragma unroll
  for (int c = 0; c < 7; ++c) se += expf(f[c] - mx);
  float lse = logf(se) + mx;
#pragma unroll
  for (int c = 0; c < 7; ++c) logp[(size_t)i * 7 + c] = f[c] - lse;
}

// fused: grp[g][c] = sum_i a[i][g]*nf2[i][c]; nag via CSC in-edge sums; + fill
__global__ __launch_bounds__(256) void k_nagrp(
    const int* __restrict__ off, const int* __restrict__ erow,
    const float* __restrict__ assign, const float* __restrict__ nf2,
    float* __restrict__ grp, float* __restrict__ nag, int N,
    float* __restrict__ adj, size_t fo, size_t fc) {
  float p[18];
#pragma unroll
  for (int q = 0; q < 18; ++q) p[q] = 0.f;
  int stride = gridDim.x * blockDim.x;
  for (int node = blockIdx.x * blockDim.x + threadIdx.x; node < N; node += stride) {
    float a0 = assign[2 * node], a1 = assign[2 * node + 1];
    float f[7];
#pragma unroll
    for (int c = 0; c < 7; ++c) f[c] = nf2[(size_t)node * 7 + c];
#pragma unroll
    for (int c = 0; c < 7; ++c) {
      p[c] = fmaf(a0, f[c], p[c]);
      p[7 + c] = fmaf(a1, f[c], p[7 + c]);
    }
    float s0 = 0.f, s1 = 0.f;
    int beg = off[node], end = off[node + 1];
    for (int j = beg; j < end; ++j) {
      int r = erow[j];
      s0 += assign[2 * r];
      s1 += assign[2 * r + 1];
    }
    p[14] = fmaf(s0, a0, p[14]);
    p[15] = fmaf(s0, a1, p[15]);
    p[16] = fmaf(s1, a0, p[16]);
    p[17] = fmaf(s1, a1, p[17]);
  }
#pragma unroll
  for (int q = 0; q < 18; ++q) {
    float v = p[q];
    v += __shfl_down(v, 32);
    v += __shfl_down(v, 16);
    v += __shfl_down(v, 8);
    v += __shfl_down(v, 4);
    v += __shfl_down(v, 2);
    v += __shfl_down(v, 1);
    p[q] = v;
  }
  __shared__ float part[4][18];
  int wid = threadIdx.x >> 6, lane = threadIdx.x & 63;
  if (lane == 0) {
#pragma unroll
    for (int q = 0; q < 18; ++q) part[wid][q] = p[q];
  }
  __syncthreads();
  if (threadIdx.x < 18) {
    float v = part[0][threadIdx.x] + part[1][threadIdx.x] +
              part[2][threadIdx.x] + part[3][threadIdx.x];
    if (threadIdx.x < 14) atomicAdd(&grp[threadIdx.x], v);
    else atomicAdd(&nag[threadIdx.x - 14], v);
  }
  fill_tail(adj, fo, fc, blockIdx.x * blockDim.x + threadIdx.x,
            gridDim.x * blockDim.x);
}

// adj scatter only (uncontended, fire-and-forget atomics)
__global__ void k_adj(const int* __restrict__ row, const int* __restrict__ col,
                      const float* __restrict__ keep, float* __restrict__ adj,
                      int N, int E) {
  int e = blockIdx.x * blockDim.x + threadIdx.x;
  if (e >= E) return;
  int r = row[e], c = col[e];
  if (keep[r] != 0.f) atomicAdd(&adj[(size_t)r * N + c], 1.0f);
}

__global__ void k_final(const float* __restrict__ grp, const float* __restrict__ nag,
                        float* __restrict__ o_ge, float* __restrict__ o_pos,
                        float* __restrict__ o_neg, float* __restrict__ o_pp) {
  int t = threadIdx.x;
  if (t < 7) {
    float g0 = grp[t], g1 = grp[7 + t];
    o_pos[t] = fminf(fmaxf(g0, -100.f), 100.f);
    o_neg[t] = fminf(fmaxf(g1, -100.f), 100.f);
    o_ge[t] = 0.5f * (g0 + g1);
  }
  if (t == 0) {
    float n00 = nag[0], n01 = nag[1], n10 = nag[2], n11 = nag[3];
    float d0 = n00 / fmaxf(fabsf(n00) + fabsf(n01), 1e-12f);
    float d1 = n11 / fmaxf(fabsf(n10) + fabsf(n11), 1e-12f);
    o_pp[0] = 0.5f * ((d0 - 1.f) * (d0 - 1.f) + (d1 - 1.f) * (d1 - 1.f));
  }
}

extern "C" void kernel_launch(void* const* d_in, const int* in_sizes, int n_in,
                              void* d_out, int out_size, void* d_ws, size_t ws_size,
                              hipStream_t stream) {
  const float* x   = (const float*)d_in[0];
  const int*   ei  = (const int*)d_in[1];
  const float* ew  = (const float*)d_in[2];
  const float* W1  = (const float*)d_in[3];
  const float* b1  = (const float*)d_in[4];
  const float* W2  = (const float*)d_in[5];
  const float* b2  = (const float*)d_in[6];
  const float* Wf1 = (const float*)d_in[7];
  const float* bf1 = (const float*)d_in[8];
  const float* Wf2 = (const float*)d_in[9];
  const float* bf2 = (const float*)d_in[10];

  const int E = in_sizes[2];
  const int F = in_sizes[3] / 16;  // 512
  const int N = in_sizes[0] / F;   // 8192
  const int* row = ei;
  const int* col = ei + E;

  float* ws = (float*)d_ws;
  float* deg    = ws; ws += N;
  float* dinv   = ws; ws += N;
  int*   cnt    = (int*)ws; ws += N;
  int*   off    = (int*)ws; ws += N + 1;
  int*   cur    = (int*)ws; ws += N;
  int*   erow   = (int*)ws; ws += E;
  float* ewt    = ws; ws += E;
  float* hw1    = ws; ws += (size_t)N * 16;
  float* acc1   = ws; ws += (size_t)N * 16;
  float* hw2    = ws; ws += (size_t)N * 7;
  float* assign = ws; ws += (size_t)N * 2;
  float* keep   = ws; ws += N;
  float* grp    = ws; ws += 16;
  float* nag    = ws; ws += 8;

  float* out = (float*)d_out;
  size_t NN = (size_t)N * N;
  float* o_adj  = out;
  float* o_nf2  = out + NN;
  float* o_ge   = o_nf2 + (size_t)N * 7;
  float* o_pos  = o_ge + 7;
  float* o_neg  = o_pos + 7;
  float* o_pp   = o_neg + 7;
  float* o_logp = o_pp + 1;

  int nb_N = (N + 255) / 256;
  int nb_E = (E + 255) / 256;
  int nb_W = (N + 3) / 4;  // one wave per node, 4 waves/block

  // fill-chunk layout (float4 units) over adj (NN/4 total)
  size_t n4 = NN / 4;
  size_t cH = 524288, cF = 524288, cGm = 1310720,
         cA = 1048576, cB = 1048576, cNg = 262144;
  size_t oH = 0, oF = oH + cH, oGm = oF + cF, oA = oGm + cGm,
         oB = oA + cA, oNg = oB + cB, oZ = oNg + cNg;
  size_t cZ = n4 - oZ;

  k_zero<<<4096, 256, 0, stream>>>(o_adj, oZ, cZ);
  k_init<<<nb_N, 256, 0, stream>>>(deg, cnt, N);
  k_hist<<<nb_E, 256, 0, stream>>>(col, ew, cnt, deg, E, o_adj, oH, cH);
  k_scan<<<1, 1024, 0, stream>>>(deg, dinv, cnt, off, cur, grp, nag, N, E);
  k_fill<<<nb_E, 256, 0, stream>>>(row, col, ew, cur, erow, ewt, E, o_adj, oF, cF);
  k_gemm1<<<N / 16, 256, 0, stream>>>(x, W1, hw1, N, o_adj, oGm, cGm);
  k_gather1<<<nb_W, 256, 0, stream>>>(off, erow, ewt, dinv, hw1, b1, acc1, N,
                                      o_adj, oA, cA);
  k_p1<<<nb_N, 256, 0, stream>>>(acc1, W2, hw2, N);
  k_gather2<<<nb_W, 256, 0, stream>>>(off, erow, ewt, dinv, hw2, b2, o_nf2, N,
                                      o_adj, oB, cB);
  k_p2<<<nb_N, 256, 0, stream>>>(o_nf2, Wf1, bf1, Wf2, bf2, assign, keep, o_logp, N);
  k_nagrp<<<32, 256, 0, stream>>>(off, erow, assign, o_nf2, grp, nag, N,
                                  o_adj, oNg, cNg);
  k_adj<<<nb_E, 256, 0, stream>>>(row, col, keep, o_adj, N, E);
  k_final<<<1, 64, 0, stream>>>(grp, nag, o_ge, o_pos, o_neg, o_pp);
}

// Round 10
// 156.250 us; speedup vs baseline: 1.2449x; 1.0733x over previous
//
#include <hip/hip_runtime.h>
#include <hip/hip_bf16.h>

// N=8192, E=262144, F=512, H=16, C=7, G=2 (shapes fixed by the problem)

typedef float vfloat4 __attribute__((ext_vector_type(4)));

// streaming zero-store helper: nt + sc0/sc1 (best measured flavor for the
// MALL-resident adj buffer). idx/cnt in float4 units.
__device__ __forceinline__ void fill_tail(float* __restrict__ adj,
                                          size_t start, size_t count,
                                          unsigned tid, unsigned nthr) {
  vfloat4 z = {0.f, 0.f, 0.f, 0.f};
  for (size_t i = start + tid; i < start + count; i += nthr) {
    float* addr = adj + i * 4;
    asm volatile("global_store_dwordx4 %0, %1, off sc0 sc1 nt"
                 :: "v"(addr), "v"(z) : "memory");
  }
}

__global__ void k_init(float* deg, int* cnt, int N,
                       float* __restrict__ adj, size_t fo, size_t fc) {
  int i = blockIdx.x * blockDim.x + threadIdx.x;
  if (i < N) { deg[i] = 1.0f; cnt[i] = 0; }  // self-loop weight 1 in deg
  fill_tail(adj, fo, fc, blockIdx.x * blockDim.x + threadIdx.x,
            gridDim.x * blockDim.x);
}

// residual zero-fill of adj
__global__ __launch_bounds__(256) void k_zero(float* __restrict__ p,
                                              size_t start, size_t count) {
  fill_tail(p, start, count,
            blockIdx.x * blockDim.x + threadIdx.x, gridDim.x * blockDim.x);
}

// histogram of edge destinations + weighted degree + fill slice
__global__ void k_hist(const int* __restrict__ col, const float* __restrict__ w,
                       int* cnt, float* deg, int E,
                       float* __restrict__ adj, size_t fo, size_t fc) {
  int e = blockIdx.x * blockDim.x + threadIdx.x;
  if (e < E) {
    int c = col[e];
    atomicAdd(&cnt[c], 1);
    atomicAdd(&deg[c], w[e]);
  }
  fill_tail(adj, fo, fc, blockIdx.x * blockDim.x + threadIdx.x,
            gridDim.x * blockDim.x);
}

// fused: dinv = deg^-1/2; exclusive scan cnt -> off/cur; zero grp/nag
__global__ __launch_bounds__(1024) void k_scan(const float* __restrict__ deg,
                                               float* __restrict__ dinv,
                                               const int* __restrict__ cnt,
                                               int* __restrict__ off,
                                               int* __restrict__ cur,
                                               float* grp, float* nag, int N, int E) {
  int t = threadIdx.x;
  if (t < 14) grp[t] = 0.f;
  if (t < 4) nag[t] = 0.f;
  int base = t * 8;
#pragma unroll
  for (int j = 0; j < 8; ++j) {
    int idx = base + j;
    if (idx < N) {
      float d = deg[idx];
      dinv[idx] = (d > 0.f) ? (1.0f / sqrtf(d)) : 0.f;
    }
  }
  __shared__ int sums[1024];
  int l[8];
  int s = 0;
#pragma unroll
  for (int j = 0; j < 8; ++j) {
    l[j] = s;
    int idx = base + j;
    s += (idx < N) ? cnt[idx] : 0;
  }
  sums[t] = s;
  __syncthreads();
  for (int d = 1; d < 1024; d <<= 1) {
    int v = (t >= d) ? sums[t - d] : 0;
    __syncthreads();
    sums[t] += v;
    __syncthreads();
  }
  int chunkoff = sums[t] - s;
#pragma unroll
  for (int j = 0; j < 8; ++j) {
    int idx = base + j;
    if (idx < N) {
      int o = chunkoff + l[j];
      off[idx] = o;
      cur[idx] = o;
    }
  }
  if (t == 0) off[N] = E;
}

// scatter edges into CSC order + fill slice
__global__ void k_fill(const int* __restrict__ row, const int* __restrict__ col,
                       const float* __restrict__ w, int* cur,
                       int* __restrict__ erow, float* __restrict__ ewt, int E,
                       float* __restrict__ adj, size_t fo, size_t fc) {
  int e = blockIdx.x * blockDim.x + threadIdx.x;
  if (e < E) {
    int c = col[e];
    int p = atomicAdd(&cur[c], 1);
    erow[p] = row[e];
    ewt[p] = w[e];
  }
  fill_tail(adj, fo, fc, blockIdx.x * blockDim.x + threadIdx.x,
            gridDim.x * blockDim.x);
}

// hw1 = x @ W1  + fill slice
__global__ __launch_bounds__(256) void k_gemm1(
    const float* __restrict__ x, const float* __restrict__ W1,
    float* __restrict__ hw1, int N,
    float* __restrict__ adj, size_t fo, size_t fc) {
  __shared__ float W1s[512 * 16];
  for (int i = threadIdx.x; i < 512 * 16; i += 256) W1s[i] = W1[i];
  __syncthreads();
  int row = blockIdx.x * 16 + (threadIdx.x >> 4);
  int h = threadIdx.x & 15;
  const float4* xr = reinterpret_cast<const float4*>(x + (size_t)row * 512);
  float acc = 0.f;
#pragma unroll 8
  for (int k4 = 0; k4 < 128; ++k4) {
    float4 v = xr[k4];
    const float* wk = &W1s[k4 * 64 + h];
    acc = fmaf(v.x, wk[0], acc);
    acc = fmaf(v.y, wk[16], acc);
    acc = fmaf(v.z, wk[32], acc);
    acc = fmaf(v.w, wk[48], acc);
  }
  hw1[(size_t)row * 16 + h] = acc;
  fill_tail(adj, fo, fc, blockIdx.x * blockDim.x + threadIdx.x,
            gridDim.x * blockDim.x);
}

// conv1 gather + fill slice
__global__ __launch_bounds__(256) void k_gather1(
    const int* __restrict__ off, const int* __restrict__ erow,
    const float* __restrict__ ewt, const float* __restrict__ dinv,
    const float* __restrict__ hw1, const float* __restrict__ b1,
    float* __restrict__ acc1, int N,
    float* __restrict__ adj, size_t fo, size_t fc) {
  int node = blockIdx.x * 4 + (threadIdx.x >> 6);
  int lane = threadIdx.x & 63;
  int s = lane >> 4, h = lane & 15;
  int beg = off[node], end = off[node + 1];
  float acc = 0.f;
  for (int j = beg + s; j < end; j += 4) {
    int r = erow[j];
    float cf = dinv[r] * ewt[j];
    acc = fmaf(hw1[(size_t)r * 16 + h], cf, acc);
  }
  acc += __shfl_down(acc, 32);
  acc += __shfl_down(acc, 16);
  if (s == 0) {
    float di = dinv[node];
    float self = hw1[(size_t)node * 16 + h];
    acc1[(size_t)node * 16 + h] = b1[h] + di * acc + di * di * self;
  }
  fill_tail(adj, fo, fc, blockIdx.x * blockDim.x + threadIdx.x,
            gridDim.x * blockDim.x);
}

// nf1 = relu(acc1); hw2 = nf1 @ W2  + fill slice
__global__ void k_p1(const float* __restrict__ acc1, const float* __restrict__ W2,
                     float* __restrict__ hw2, int N,
                     float* __restrict__ adj, size_t fo, size_t fc) {
  __shared__ float W2s[16 * 7];
  if (threadIdx.x < 112) W2s[threadIdx.x] = W2[threadIdx.x];
  __syncthreads();
  int i = blockIdx.x * blockDim.x + threadIdx.x;
  if (i < N) {
    float v[16];
#pragma unroll
    for (int h = 0; h < 16; ++h) v[h] = fmaxf(acc1[(size_t)i * 16 + h], 0.f);
#pragma unroll
    for (int c = 0; c < 7; ++c) {
      float s = 0.f;
#pragma unroll
      for (int h = 0; h < 16; ++h) s = fmaf(v[h], W2s[h * 7 + c], s);
      hw2[(size_t)i * 7 + c] = s;
    }
  }
  fill_tail(adj, fo, fc, blockIdx.x * blockDim.x + threadIdx.x,
            gridDim.x * blockDim.x);
}

// conv2 gather + fill slice
__global__ __launch_bounds__(256) void k_gather2(
    const int* __restrict__ off, const int* __restrict__ erow,
    const float* __restrict__ ewt, const float* __restrict__ dinv,
    const float* __restrict__ hw2, const float* __restrict__ b2,
    float* __restrict__ nf2, int N,
    float* __restrict__ adj, size_t fo, size_t fc) {
  int node = blockIdx.x * 4 + (threadIdx.x >> 6);
  int lane = threadIdx.x & 63;
  int s = lane >> 3, c = lane & 7;
  int beg = off[node], end = off[node + 1];
  float acc = 0.f;
  if (c < 7) {
    for (int j = beg + s; j < end; j += 8) {
      int r = erow[j];
      float cf = dinv[r] * ewt[j];
      acc = fmaf(hw2[(size_t)r * 7 + c], cf, acc);
    }
  }
  acc += __shfl_down(acc, 32);
  acc += __shfl_down(acc, 16);
  acc += __shfl_down(acc, 8);
  if (s == 0 && c < 7) {
    float di = dinv[node];
    nf2[(size_t)node * 7 + c] = b2[c] + di * acc + di * di * hw2[(size_t)node * 7 + c];
  }
  fill_tail(adj, fo, fc, blockIdx.x * blockDim.x + threadIdx.x,
            gridDim.x * blockDim.x);
}

// per-node: assignment (softmax over 2), keep mask, logp  + fill slice
__global__ void k_p2(const float* __restrict__ nf2,
                     const float* __restrict__ Wf1, const float* __restrict__ bf1,
                     const float* __restrict__ Wf2, const float* __restrict__ bf2,
                     float* __restrict__ assign, float* __restrict__ keep,
                     float* __restrict__ logp, int N,
                     float* __restrict__ adj, size_t fo, size_t fc) {
  __shared__ float Wf1s[7 * 16], bf1s[16], Wf2s[16 * 2], bf2s[2];
  if (threadIdx.x < 112) Wf1s[threadIdx.x] = Wf1[threadIdx.x];
  if (threadIdx.x < 16) bf1s[threadIdx.x] = bf1[threadIdx.x];
  if (threadIdx.x < 32) Wf2s[threadIdx.x] = Wf2[threadIdx.x];
  if (threadIdx.x < 2) bf2s[threadIdx.x] = bf2[threadIdx.x];
  __syncthreads();
  int i = blockIdx.x * blockDim.x + threadIdx.x;
  if (i < N) {
    float f[7];
#pragma unroll
    for (int c = 0; c < 7; ++c) f[c] = nf2[(size_t)i * 7 + c];
    float z0 = bf2s[0], z1 = bf2s[1];
#pragma unroll
    for (int h = 0; h < 16; ++h) {
      float s = bf1s[h];
#pragma unroll
      for (int c = 0; c < 7; ++c) s = fmaf(f[c], Wf1s[c * 16 + h], s);
      float a = tanhf(s);
      z0 = fmaf(a, Wf2s[h * 2 + 0], z0);
      z1 = fmaf(a, Wf2s[h * 2 + 1], z1);
    }
    float m = fmaxf(z0, z1);
    float e0 = expf(z0 - m), e1 = expf(z1 - m);
    float inv = 1.f / (e0 + e1);
    float a0 = e0 * inv, a1 = e1 * inv;
    assign[2 * i] = a0;
    assign[2 * i + 1] = a1;
    keep[i] = (a0 >= a1) ? 1.f : 0.f;
    float mx = f[0];
#pragma unroll
    for (int c = 1; c < 7; ++c) mx = fmaxf(mx, f[c]);
    float se = 0.f;
#pragma unroll
    for (int c = 0; c < 7; ++c) se += expf(f[c] - mx);
    float lse = logf(se) + mx;
#pragma unroll
    for (int c = 0; c < 7; ++c) logp[(size_t)i * 7 + c] = f[c] - lse;
  }
  fill_tail(adj, fo, fc, blockIdx.x * blockDim.x + threadIdx.x,
            gridDim.x * blockDim.x);
}

// fused: grp[g][c] = sum_i a[i][g]*nf2[i][c]; nag via CSC in-edge sums; + fill
__global__ __launch_bounds__(256) void k_nagrp(
    const int* __restrict__ off, const int* __restrict__ erow,
    const float* __restrict__ assign, const float* __restrict__ nf2,
    float* __restrict__ grp, float* __restrict__ nag, int N,
    float* __restrict__ adj, size_t fo, size_t fc) {
  float p[18];
#pragma unroll
  for (int q = 0; q < 18; ++q) p[q] = 0.f;
  int stride = gridDim.x * blockDim.x;
  for (int node = blockIdx.x * blockDim.x + threadIdx.x; node < N; node += stride) {
    float a0 = assign[2 * node], a1 = assign[2 * node + 1];
    float f[7];
#pragma unroll
    for (int c = 0; c < 7; ++c) f[c] = nf2[(size_t)node * 7 + c];
#pragma unroll
    for (int c = 0; c < 7; ++c) {
      p[c] = fmaf(a0, f[c], p[c]);
      p[7 + c] = fmaf(a1, f[c], p[7 + c]);
    }
    float s0 = 0.f, s1 = 0.f;
    int beg = off[node], end = off[node + 1];
    for (int j = beg; j < end; ++j) {
      int r = erow[j];
      s0 += assign[2 * r];
      s1 += assign[2 * r + 1];
    }
    p[14] = fmaf(s0, a0, p[14]);
    p[15] = fmaf(s0, a1, p[15]);
    p[16] = fmaf(s1, a0, p[16]);
    p[17] = fmaf(s1, a1, p[17]);
  }
#pragma unroll
  for (int q = 0; q < 18; ++q) {
    float v = p[q];
    v += __shfl_down(v, 32);
    v += __shfl_down(v, 16);
    v += __shfl_down(v, 8);
    v += __shfl_down(v, 4);
    v += __shfl_down(v, 2);
    v += __shfl_down(v, 1);
    p[q] = v;
  }
  __shared__ float part[4][18];
  int wid = threadIdx.x >> 6, lane = threadIdx.x & 63;
  if (lane == 0) {
#pragma unroll
    for (int q = 0; q < 18; ++q) part[wid][q] = p[q];
  }
  __syncthreads();
  if (threadIdx.x < 18) {
    float v = part[0][threadIdx.x] + part[1][threadIdx.x] +
              part[2][threadIdx.x] + part[3][threadIdx.x];
    if (threadIdx.x < 14) atomicAdd(&grp[threadIdx.x], v);
    else atomicAdd(&nag[threadIdx.x - 14], v);
  }
  fill_tail(adj, fo, fc, blockIdx.x * blockDim.x + threadIdx.x,
            gridDim.x * blockDim.x);
}

// adj scatter only (uncontended, fire-and-forget atomics)
__global__ void k_adj(const int* __restrict__ row, const int* __restrict__ col,
                      const float* __restrict__ keep, float* __restrict__ adj,
                      int N, int E) {
  int e = blockIdx.x * blockDim.x + threadIdx.x;
  if (e >= E) return;
  int r = row[e], c = col[e];
  if (keep[r] != 0.f) atomicAdd(&adj[(size_t)r * N + c], 1.0f);
}

__global__ void k_final(const float* __restrict__ grp, const float* __restrict__ nag,
                        float* __restrict__ o_ge, float* __restrict__ o_pos,
                        float* __restrict__ o_neg, float* __restrict__ o_pp) {
  int t = threadIdx.x;
  if (t < 7) {
    float g0 = grp[t], g1 = grp[7 + t];
    o_pos[t] = fminf(fmaxf(g0, -100.f), 100.f);
    o_neg[t] = fminf(fmaxf(g1, -100.f), 100.f);
    o_ge[t] = 0.5f * (g0 + g1);
  }
  if (t == 0) {
    float n00 = nag[0], n01 = nag[1], n10 = nag[2], n11 = nag[3];
    float d0 = n00 / fmaxf(fabsf(n00) + fabsf(n01), 1e-12f);
    float d1 = n11 / fmaxf(fabsf(n10) + fabsf(n11), 1e-12f);
    o_pp[0] = 0.5f * ((d0 - 1.f) * (d0 - 1.f) + (d1 - 1.f) * (d1 - 1.f));
  }
}

extern "C" void kernel_launch(void* const* d_in, const int* in_sizes, int n_in,
                              void* d_out, int out_size, void* d_ws, size_t ws_size,
                              hipStream_t stream) {
  const float* x   = (const float*)d_in[0];
  const int*   ei  = (const int*)d_in[1];
  const float* ew  = (const float*)d_in[2];
  const float* W1  = (const float*)d_in[3];
  const float* b1  = (const float*)d_in[4];
  const float* W2  = (const float*)d_in[5];
  const float* b2  = (const float*)d_in[6];
  const float* Wf1 = (const float*)d_in[7];
  const float* bf1 = (const float*)d_in[8];
  const float* Wf2 = (const float*)d_in[9];
  const float* bf2 = (const float*)d_in[10];

  const int E = in_sizes[2];
  const int F = in_sizes[3] / 16;  // 512
  const int N = in_sizes[0] / F;   // 8192
  const int* row = ei;
  const int* col = ei + E;

  float* ws = (float*)d_ws;
  float* deg    = ws; ws += N;
  float* dinv   = ws; ws += N;
  int*   cnt    = (int*)ws; ws += N;
  int*   off    = (int*)ws; ws += N + 1;
  int*   cur    = (int*)ws; ws += N;
  int*   erow   = (int*)ws; ws += E;
  float* ewt    = ws; ws += E;
  float* hw1    = ws; ws += (size_t)N * 16;
  float* acc1   = ws; ws += (size_t)N * 16;
  float* hw2    = ws; ws += (size_t)N * 7;
  float* assign = ws; ws += (size_t)N * 2;
  float* keep   = ws; ws += N;
  float* grp    = ws; ws += 16;
  float* nag    = ws; ws += 8;

  float* out = (float*)d_out;
  size_t NN = (size_t)N * N;
  float* o_adj  = out;
  float* o_nf2  = out + NN;
  float* o_ge   = o_nf2 + (size_t)N * 7;
  float* o_pos  = o_ge + 7;
  float* o_neg  = o_pos + 7;
  float* o_pp   = o_neg + 7;
  float* o_logp = o_pp + 1;

  int nb_N = (N + 255) / 256;
  int nb_E = (E + 255) / 256;
  int nb_W = (N + 3) / 4;  // one wave per node, 4 waves/block

  // fill-chunk layout (float4 units) over adj (NN/4 = 16,777,216 total)
  size_t n4 = NN / 4;
  size_t cI  = 524288;    // k_init   (8 MB)
  size_t cH  = 1572864;   // k_hist   (24 MB)
  size_t cF  = 1572864;   // k_fill   (24 MB)
  size_t cGm = 2621440;   // k_gemm1  (40 MB)
  size_t cA  = 2621440;   // k_gather1(40 MB)
  size_t cP1 = 524288;    // k_p1     (8 MB)
  size_t cB  = 2621440;   // k_gather2(40 MB)
  size_t cP2 = 524288;    // k_p2     (8 MB)
  size_t cNg = 524288;    // k_nagrp  (8 MB)
  size_t oI = 0, oH = oI + cI, oF = oH + cH, oGm = oF + cF, oA = oGm + cGm,
         oP1 = oA + cA, oB = oP1 + cP1, oP2 = oB + cB, oNg = oP2 + cP2,
         oZ = oNg + cNg;
  size_t cZ = n4 - oZ;   // residual (~56 MB)

  k_zero<<<4096, 256, 0, stream>>>(o_adj, oZ, cZ);
  k_init<<<512, 256, 0, stream>>>(deg, cnt, N, o_adj, oI, cI);
  k_hist<<<nb_E, 256, 0, stream>>>(col, ew, cnt, deg, E, o_adj, oH, cH);
  k_scan<<<1, 1024, 0, stream>>>(deg, dinv, cnt, off, cur, grp, nag, N, E);
  k_fill<<<nb_E, 256, 0, stream>>>(row, col, ew, cur, erow, ewt, E, o_adj, oF, cF);
  k_gemm1<<<N / 16, 256, 0, stream>>>(x, W1, hw1, N, o_adj, oGm, cGm);
  k_gather1<<<nb_W, 256, 0, stream>>>(off, erow, ewt, dinv, hw1, b1, acc1, N,
                                      o_adj, oA, cA);
  k_p1<<<nb_N, 256, 0, stream>>>(acc1, W2, hw2, N, o_adj, oP1, cP1);
  k_gather2<<<nb_W, 256, 0, stream>>>(off, erow, ewt, dinv, hw2, b2, o_nf2, N,
                                      o_adj, oB, cB);
  k_p2<<<nb_N, 256, 0, stream>>>(o_nf2, Wf1, bf1, Wf2, bf2, assign, keep, o_logp, N,
                                 o_adj, oP2, cP2);
  k_nagrp<<<32, 256, 0, stream>>>(off, erow, assign, o_nf2, grp, nag, N,
                                  o_adj, oNg, cNg);
  k_adj<<<nb_E, 256, 0, stream>>>(row, col, keep, o_adj, N, E);
  k_final<<<1, 64, 0, stream>>>(grp, nag, o_ge, o_pos, o_neg, o_pp);
}